// Round 1
// baseline (164.185 us; speedup 1.0000x reference)
//
#include <hip/hip_runtime.h>
#include <math.h>

// GlobalMultiHeadAttention collapses: softmax over the size-1 summary axis is
// identically 1.0, so q/Wq/Wk/bias-MLP/mask are dead. Remaining math:
//   summary[bn,:]  = sum_t m*x[bn,t,:] / max(sum_t m, 1e-6)
//   v[bn,:]        = summary @ Wv + bv
//   ps[bn,:]       = sum_t m*pos[bn,t,:] / denom
//   rf[bn,t]       = [dx,dy,dz,||d||,||d||^2],  d = pos[bn,t]-ps[bn]
//   rel_val[bn,t,:] = gelu_exact(rf @ Vw1 + Vb1) @ Vw2 + Vb2
//   out[bn,t,:]    = x[bn,t,:] + v[bn,:] + rel_val[bn,t,:]
//
// Shapes: BN=512, T=256, D=256, HIDDEN=128. All f32.

#define BN_TOT 512
#define T_DIM 256
#define D_DIM 256
#define HID 128

// ---------------- K1: per-bn masked means + v = summary @ Wv + bv ----------
__global__ __launch_bounds__(1024) void k_summary(
    const float* __restrict__ x,      // [BN,T,D]
    const int* __restrict__ masks,    // [BN,T]
    const float* __restrict__ pos,    // [BN,T,3]
    const float* __restrict__ Wv,     // [D,D]
    const float* __restrict__ bv,     // [D]
    float* __restrict__ v_out,        // [BN,D]
    float* __restrict__ ps_out)       // [BN,4]  (x,y,z,pad)
{
    __shared__ float s_part[16 * 256];   // 16 KB
    __shared__ float s_red[4 * 256];     // 4 KB: count, mpx, mpy, mpz
    __shared__ float s_sum[256];         // summary (scaled)

    const int bn  = blockIdx.x;
    const int tid = threadIdx.x;
    const int dq  = tid & 63;   // d-chunk of 4 floats
    const int tq  = tid >> 6;   // t-group of 16 tokens (16 groups)

    const float* xb = x + (size_t)bn * T_DIM * D_DIM;
    const int*   mb = masks + bn * T_DIM;

    // ---- masked column sums (float4 along d) ----
    float4 a = make_float4(0.f, 0.f, 0.f, 0.f);
    for (int t = tq * 16; t < tq * 16 + 16; ++t) {
        float m = (float)mb[t];                       // wave-uniform
        float4 xv = *reinterpret_cast<const float4*>(xb + t * D_DIM + dq * 4);
        a.x += m * xv.x; a.y += m * xv.y; a.z += m * xv.z; a.w += m * xv.w;
    }
    *reinterpret_cast<float4*>(s_part + tq * 256 + dq * 4) = a;

    // ---- mask count + masked position sums (per-token partials) ----
    if (tid < 256) {
        float m = (float)mb[tid];
        const float* pp = pos + ((size_t)bn * T_DIM + tid) * 3;
        s_red[0 * 256 + tid] = m;
        s_red[1 * 256 + tid] = m * pp[0];
        s_red[2 * 256 + tid] = m * pp[1];
        s_red[3 * 256 + tid] = m * pp[2];
    }
    __syncthreads();
    for (int off = 128; off > 0; off >>= 1) {
        if (tid < off) {
            s_red[0 * 256 + tid] += s_red[0 * 256 + tid + off];
            s_red[1 * 256 + tid] += s_red[1 * 256 + tid + off];
            s_red[2 * 256 + tid] += s_red[2 * 256 + tid + off];
            s_red[3 * 256 + tid] += s_red[3 * 256 + tid + off];
        }
        __syncthreads();
    }
    const float inv = 1.0f / fmaxf(s_red[0], 1e-6f);
    if (tid < 3) ps_out[bn * 4 + tid] = s_red[(tid + 1) * 256] * inv;

    if (tid < 256) {
        float s = 0.f;
        #pragma unroll
        for (int q = 0; q < 16; ++q) s += s_part[q * 256 + tid];
        s_sum[tid] = s * inv;     // summary[bn, tid]
    }
    __syncthreads();

    // ---- v = summary @ Wv + bv (split K=256 into 16 groups of 16) ----
    float4 va = make_float4(0.f, 0.f, 0.f, 0.f);
    for (int c = tq * 16; c < tq * 16 + 16; ++c) {
        float sc = s_sum[c];
        float4 wv = *reinterpret_cast<const float4*>(Wv + c * D_DIM + dq * 4);
        va.x += sc * wv.x; va.y += sc * wv.y; va.z += sc * wv.z; va.w += sc * wv.w;
    }
    __syncthreads();   // make sure everyone is done reading s_part for s_sum
    *reinterpret_cast<float4*>(s_part + tq * 256 + dq * 4) = va;
    __syncthreads();
    if (tid < 256) {
        float r = bv[tid];
        #pragma unroll
        for (int q = 0; q < 16; ++q) r += s_part[q * 256 + tid];
        v_out[bn * D_DIM + tid] = r;
    }
}

// ---------------- K3: rel-feat MLP + residual output ----------------------
// grid: (4, 512) -> (token-group of 64, bn); block: 256 threads
__global__ __launch_bounds__(256) void k_main(
    const float* __restrict__ x,
    const float* __restrict__ pos,
    const float* __restrict__ Vw1,   // [5,128]
    const float* __restrict__ Vb1,   // [128]
    const float* __restrict__ Vw2,   // [128,256]
    const float* __restrict__ Vb2,   // [256]
    const float* __restrict__ v_in,  // [BN,256]
    const float* __restrict__ ps_in, // [BN,4]
    float* __restrict__ out)
{
    __shared__ float s_h[HID * 68];   // hidden, transposed [c][tok], stride 68 (16B-aligned rows, banks spread)
    __shared__ float s_rf[64 * 6];    // rel features per token (stride 6)
    __shared__ float s_v[256];

    const int tg  = blockIdx.x;        // token group (64 tokens)
    const int bn  = blockIdx.y;
    const int tid = threadIdx.x;
    const int t0  = tg * 64;

    s_v[tid] = v_in[bn * D_DIM + tid];
    const float psx = ps_in[bn * 4 + 0];
    const float psy = ps_in[bn * 4 + 1];
    const float psz = ps_in[bn * 4 + 2];

    if (tid < 64) {
        const float* pp = pos + ((size_t)bn * T_DIM + t0 + tid) * 3;
        float dx = pp[0] - psx, dy = pp[1] - psy, dz = pp[2] - psz;
        float d2 = dx * dx + dy * dy + dz * dz;
        float* rf = s_rf + tid * 6;
        rf[0] = dx; rf[1] = dy; rf[2] = dz; rf[3] = sqrtf(d2); rf[4] = d2;
    }
    __syncthreads();

    // ---- hidden = gelu_exact(rf @ Vw1 + Vb1), stored transposed [c][tok] ----
    {
        const int c  = tid >> 1;           // 0..127
        const int th = tid & 1;            // two halves of 32 tokens
        const float w0 = Vw1[0 * HID + c], w1 = Vw1[1 * HID + c],
                    w2 = Vw1[2 * HID + c], w3 = Vw1[3 * HID + c],
                    w4 = Vw1[4 * HID + c];
        const float b1 = Vb1[c];
        for (int j = 0; j < 32; ++j) {
            const int tk = th * 32 + j;
            const float* rf = s_rf + tk * 6;
            float z = b1 + rf[0] * w0 + rf[1] * w1 + rf[2] * w2 + rf[3] * w3 + rf[4] * w4;
            float g = 0.5f * z * (1.0f + erff(z * 0.70710678118654752f));
            s_h[c * 68 + tk] = g;
        }
    }
    __syncthreads();

    // ---- rel_val = hidden @ Vw2 ; out = x + v + Vb2 + rel_val ----
    // thread tile: 4 d-cols (td) x 16 tokens (tt)
    const int td = tid & 63;      // d0 = td*4
    const int tt = tid >> 6;      // token base = tt*16
    const int d0 = td * 4;
    const int tb = tt * 16;

    float acc[16][4];
    #pragma unroll
    for (int i = 0; i < 16; ++i)
        #pragma unroll
        for (int j = 0; j < 4; ++j) acc[i][j] = 0.f;

    for (int c = 0; c < HID; ++c) {
        const float4 w = *reinterpret_cast<const float4*>(Vw2 + c * D_DIM + d0);
        const float* hr = s_h + c * 68 + tb;
        float hv[16];
        #pragma unroll
        for (int i = 0; i < 4; ++i) {
            float4 h = *reinterpret_cast<const float4*>(hr + 4 * i);
            hv[4 * i + 0] = h.x; hv[4 * i + 1] = h.y;
            hv[4 * i + 2] = h.z; hv[4 * i + 3] = h.w;
        }
        #pragma unroll
        for (int i = 0; i < 16; ++i) {
            acc[i][0] += hv[i] * w.x;
            acc[i][1] += hv[i] * w.y;
            acc[i][2] += hv[i] * w.z;
            acc[i][3] += hv[i] * w.w;
        }
    }

    const float4 b2 = *reinterpret_cast<const float4*>(Vb2 + d0);
    const float4 vv = make_float4(s_v[d0], s_v[d0 + 1], s_v[d0 + 2], s_v[d0 + 3]);
    const float* xb = x + ((size_t)bn * T_DIM + t0) * D_DIM;
    float*       ob = out + ((size_t)bn * T_DIM + t0) * D_DIM;

    #pragma unroll
    for (int i = 0; i < 16; ++i) {
        const int t = tb + i;
        float4 xv = *reinterpret_cast<const float4*>(xb + t * D_DIM + d0);
        float4 o;
        o.x = xv.x + vv.x + b2.x + acc[i][0];
        o.y = xv.y + vv.y + b2.y + acc[i][1];
        o.z = xv.z + vv.z + b2.z + acc[i][2];
        o.w = xv.w + vv.w + b2.w + acc[i][3];
        *reinterpret_cast<float4*>(ob + t * D_DIM + d0) = o;
    }
}

extern "C" void kernel_launch(void* const* d_in, const int* in_sizes, int n_in,
                              void* d_out, int out_size, void* d_ws, size_t ws_size,
                              hipStream_t stream) {
    const float* x     = (const float*)d_in[0];
    // d_in[1] = sum_token (unused by reference)
    const int*   masks = (const int*)d_in[2];
    const float* pos   = (const float*)d_in[3];
    // d_in[4..7] = Wq,bq,Wk,bk (dead: softmax over size-1 axis == 1)
    const float* Wv    = (const float*)d_in[8];
    const float* bv    = (const float*)d_in[9];
    // d_in[10..13] = bias-MLP (dead)
    const float* Vw1   = (const float*)d_in[14];
    const float* Vb1   = (const float*)d_in[15];
    const float* Vw2   = (const float*)d_in[16];
    const float* Vb2   = (const float*)d_in[17];
    float* out = (float*)d_out;

    float* v_ws  = (float*)d_ws;             // [BN,256] = 512 KB
    float* ps_ws = v_ws + BN_TOT * D_DIM;    // [BN,4]   = 8 KB

    k_summary<<<BN_TOT, 1024, 0, stream>>>(x, masks, pos, Wv, bv, v_ws, ps_ws);
    k_main<<<dim3(4, BN_TOT), 256, 0, stream>>>(x, pos, Vw1, Vb1, Vw2, Vb2,
                                                v_ws, ps_ws, out);
}

// Round 2
// 100.812 us; speedup vs baseline: 1.6286x; 1.6286x over previous
//
#include <hip/hip_runtime.h>
#include <hip/hip_bf16.h>
#include <math.h>

// Collapsed math (softmax over size-1 summary axis == 1, so q/Wq/Wk/bias-MLP
// are dead):
//   summary[bn,:] = sum_t m*x / max(sum_t m, 1e-6)
//   v[bn,:]       = summary @ Wv + bv
//   rf[bn,t]      = [dx,dy,dz,||d||,||d||^2] vs masked-mean position
//   rel_val       = gelu_exact(rf @ Vw1 + Vb1) @ Vw2 + Vb2   (bf16 MFMA)
//   out[bn,t,:]   = x[bn,t,:] + v[bn,:] + rel_val[bn,t,:]
//
// One block per bn (512 blocks x 512 threads), fully fused. MFMA for the
// 256x128 @ 128x256 per-bn GEMM.

#define BN_TOT 512
#define T_DIM 256
#define D_DIM 256
#define HID 128

typedef __attribute__((ext_vector_type(8))) short short8v;
typedef __attribute__((ext_vector_type(4))) float f32x4;

static __device__ __forceinline__ ushort f2bf(float f) {
    __hip_bfloat16 h = __float2bfloat16(f);
    return *reinterpret_cast<ushort*>(&h);
}

// ---- prep: Vw2 [128][256] f32 -> Vw2t [256][128] bf16 (transposed) ----
__global__ __launch_bounds__(128) void k_prep(const float* __restrict__ Vw2,
                                              ushort* __restrict__ Vw2t) {
    const int d = blockIdx.x;      // 0..255
    const int k = threadIdx.x;     // 0..127
    Vw2t[d * HID + k] = f2bf(Vw2[k * D_DIM + d]);
}

__global__ __launch_bounds__(512, 1) void k_fused(
    const float* __restrict__ x,      // [BN,T,D]
    const int* __restrict__ masks,    // [BN,T]
    const float* __restrict__ pos,    // [BN,T,3]
    const float* __restrict__ Wv,     // [D,D]
    const float* __restrict__ bv,     // [D]
    const float* __restrict__ Vw1,    // [5,128]
    const float* __restrict__ Vb1,    // [128]
    const ushort* __restrict__ Vw2t,  // [256][128] bf16
    const float* __restrict__ Vb2,    // [256]
    float* __restrict__ out)
{
    __shared__ float s_part[8 * 256];         // 8 KB  partial sums
    __shared__ float s_red[4 * 256];          // 4 KB  count, m*px, m*py, m*pz
    __shared__ float s_m[256];                // 1 KB  mask as float
    __shared__ float s_sum[256];              // summary (scaled)
    __shared__ float s_vb[256];               // v + bv + Vb2
    __shared__ float s_rf[256 * 6];           // 6 KB  rel features
    __shared__ float s_w1[5 * 128];           // 2.5 KB
    __shared__ float s_b1[128];
    __shared__ unsigned char s_hid[T_DIM * HID * 2];  // 64 KB bf16, XOR-swizzled

    const int bn  = blockIdx.x;
    const int tid = threadIdx.x;

    const float* xb = x + (size_t)bn * T_DIM * D_DIM;
    const int*   mb = masks + bn * T_DIM;

    // ---- stage masks, per-token pos partials, Vw1/Vb1 ----
    if (tid < 256) {
        float m = (float)mb[tid];
        s_m[tid] = m;
        const float* pp = pos + ((size_t)bn * T_DIM + tid) * 3;
        float px = pp[0], py = pp[1], pz = pp[2];
        s_rf[tid * 6 + 0] = px;               // raw pos, overwritten in-place later
        s_rf[tid * 6 + 1] = py;
        s_rf[tid * 6 + 2] = pz;
        s_red[0 * 256 + tid] = m;
        s_red[1 * 256 + tid] = m * px;
        s_red[2 * 256 + tid] = m * py;
        s_red[3 * 256 + tid] = m * pz;
    }
    if (tid < 512) s_w1[tid] = Vw1[tid];
    if (tid < 128) { s_w1[512 + tid] = Vw1[512 + tid]; s_b1[tid] = Vb1[tid]; }
    __syncthreads();

    // ---- masked column sums of x ----
    {
        const int dq = tid & 63, tq = tid >> 6;   // 64 float4-chunks x 8 t-groups
        float4 a = make_float4(0.f, 0.f, 0.f, 0.f);
        #pragma unroll 4
        for (int t = tq * 32; t < tq * 32 + 32; ++t) {
            float m = s_m[t];
            float4 xv = *reinterpret_cast<const float4*>(xb + t * D_DIM + dq * 4);
            a.x += m * xv.x; a.y += m * xv.y; a.z += m * xv.z; a.w += m * xv.w;
        }
        *reinterpret_cast<float4*>(s_part + tq * 256 + dq * 4) = a;
    }
    __syncthreads();

    // ---- reduce count/pos ----
    for (int off = 128; off > 0; off >>= 1) {
        if (tid < off) {
            s_red[0 * 256 + tid] += s_red[0 * 256 + tid + off];
            s_red[1 * 256 + tid] += s_red[1 * 256 + tid + off];
            s_red[2 * 256 + tid] += s_red[2 * 256 + tid + off];
            s_red[3 * 256 + tid] += s_red[3 * 256 + tid + off];
        }
        __syncthreads();
    }
    const float inv = 1.0f / fmaxf(s_red[0], 1e-6f);
    const float psx = s_red[1 * 256] * inv;
    const float psy = s_red[2 * 256] * inv;
    const float psz = s_red[3 * 256] * inv;

    if (tid < 256) {
        float s = 0.f;
        #pragma unroll
        for (int q = 0; q < 8; ++q) s += s_part[q * 256 + tid];
        s_sum[tid] = s * inv;                         // summary[bn, tid]
        // rel features (in-place over raw pos)
        float dx = s_rf[tid * 6 + 0] - psx;
        float dy = s_rf[tid * 6 + 1] - psy;
        float dz = s_rf[tid * 6 + 2] - psz;
        float d2 = dx * dx + dy * dy + dz * dz;
        s_rf[tid * 6 + 0] = dx; s_rf[tid * 6 + 1] = dy; s_rf[tid * 6 + 2] = dz;
        s_rf[tid * 6 + 3] = sqrtf(d2); s_rf[tid * 6 + 4] = d2;
    }
    __syncthreads();

    // ---- hidden = gelu(rf @ Vw1 + Vb1) -> bf16 LDS (XOR swizzle) ----
    {
        const int cg = tid & 15;                 // channel group: c = cg*8..cg*8+7
        const int c0 = cg * 8;
        float wv[5][8], bb[8];
        #pragma unroll
        for (int e = 0; e < 5; ++e)
            #pragma unroll
            for (int j = 0; j < 8; ++j) wv[e][j] = s_w1[e * 128 + c0 + j];
        #pragma unroll
        for (int j = 0; j < 8; ++j) bb[j] = s_b1[c0 + j];

        #pragma unroll
        for (int s = 0; s < 8; ++s) {
            const int tok = (tid >> 4) + s * 32;
            const float* rf = s_rf + tok * 6;
            const float dx = rf[0], dy = rf[1], dz = rf[2], dd = rf[3], d2 = rf[4];
            uint pk[4];
            #pragma unroll
            for (int jj = 0; jj < 4; ++jj) {
                float g[2];
                #pragma unroll
                for (int h = 0; h < 2; ++h) {
                    const int j = jj * 2 + h;
                    float z = bb[j] + dx * wv[0][j] + dy * wv[1][j] + dz * wv[2][j]
                                    + dd * wv[3][j] + d2 * wv[4][j];
                    g[h] = 0.5f * z * (1.0f + erff(z * 0.70710678118654752f));
                }
                pk[jj] = (uint)f2bf(g[0]) | ((uint)f2bf(g[1]) << 16);
            }
            int byte = tok * 256 + cg * 16;
            byte ^= (tok & 7) << 4;
            *reinterpret_cast<uint4*>(s_hid + byte) = make_uint4(pk[0], pk[1], pk[2], pk[3]);
        }
    }

    // ---- v = summary @ Wv (+ bv + Vb2) ----
    {
        const int dq = tid & 63, kq = tid >> 6;
        float4 va = make_float4(0.f, 0.f, 0.f, 0.f);
        #pragma unroll 4
        for (int i = 0; i < 32; ++i) {
            const int k = kq * 32 + i;
            float sc = s_sum[k];
            float4 w = *reinterpret_cast<const float4*>(Wv + k * D_DIM + dq * 4);
            va.x += sc * w.x; va.y += sc * w.y; va.z += sc * w.z; va.w += sc * w.w;
        }
        *reinterpret_cast<float4*>(s_part + kq * 256 + dq * 4) = va;
    }
    __syncthreads();
    if (tid < 256) {
        float r = bv[tid] + Vb2[tid];
        #pragma unroll
        for (int q = 0; q < 8; ++q) r += s_part[q * 256 + tid];
        s_vb[tid] = r;
    }
    __syncthreads();

    // ---- GEMM: rel_val = hidden[256x128] @ Vw2t^T via MFMA ----
    const int l  = tid & 63;
    const int wv_id = tid >> 6;          // 8 waves
    const int wr = wv_id & 1;            // token half (128 tokens)
    const int wc = wv_id >> 1;           // d quarter (64 cols)

    f32x4 acc[8][4];
    #pragma unroll
    for (int m = 0; m < 8; ++m)
        #pragma unroll
        for (int n = 0; n < 4; ++n) acc[m][n] = (f32x4){0.f, 0.f, 0.f, 0.f};

    const ushort* bbase = Vw2t + ((size_t)(wc * 64 + (l & 15))) * HID + ((l >> 4) * 8);
    const int col16 = (l >> 4) * 16;

    #pragma unroll
    for (int ks = 0; ks < 4; ++ks) {
        short8v bfr[4];
        #pragma unroll
        for (int n = 0; n < 4; ++n)
            bfr[n] = *reinterpret_cast<const short8v*>(bbase + n * 16 * HID + ks * 32);
        short8v afr[8];
        #pragma unroll
        for (int m = 0; m < 8; ++m) {
            const int tok = wr * 128 + m * 16 + (l & 15);
            int byte = tok * 256 + ks * 64 + col16;
            byte ^= (tok & 7) << 4;
            afr[m] = *reinterpret_cast<const short8v*>(s_hid + byte);
        }
        #pragma unroll
        for (int m = 0; m < 8; ++m)
            #pragma unroll
            for (int n = 0; n < 4; ++n)
                acc[m][n] = __builtin_amdgcn_mfma_f32_16x16x32_bf16(
                    afr[m], bfr[n], acc[m][n], 0, 0, 0);
    }

    // ---- epilogue: out = x + (v+bv+Vb2) + rel_val ----
    #pragma unroll
    for (int m = 0; m < 8; ++m) {
        const int tok = wr * 128 + m * 16 + (l >> 4) * 4;
        const float* xr = xb + (size_t)tok * D_DIM;
        float*       orow = out + ((size_t)bn * T_DIM + tok) * D_DIM;
        #pragma unroll
        for (int n = 0; n < 4; ++n) {
            const int d = wc * 64 + n * 16 + (l & 15);
            const float vb = s_vb[d];
            #pragma unroll
            for (int r = 0; r < 4; ++r) {
                orow[r * D_DIM + d] = xr[r * D_DIM + d] + vb + acc[m][n][r];
            }
        }
    }
}

extern "C" void kernel_launch(void* const* d_in, const int* in_sizes, int n_in,
                              void* d_out, int out_size, void* d_ws, size_t ws_size,
                              hipStream_t stream) {
    const float* x     = (const float*)d_in[0];
    // d_in[1] = sum_token (unused by reference)
    const int*   masks = (const int*)d_in[2];
    const float* pos   = (const float*)d_in[3];
    // d_in[4..7] = Wq,bq,Wk,bk (dead: softmax over size-1 axis == 1)
    const float* Wv    = (const float*)d_in[8];
    const float* bv    = (const float*)d_in[9];
    // d_in[10..13] = bias-MLP (dead)
    const float* Vw1   = (const float*)d_in[14];
    const float* Vb1   = (const float*)d_in[15];
    const float* Vw2   = (const float*)d_in[16];
    const float* Vb2   = (const float*)d_in[17];
    float* out = (float*)d_out;

    ushort* Vw2t = (ushort*)d_ws;   // 64 KB

    k_prep<<<D_DIM, HID, 0, stream>>>(Vw2, Vw2t);
    k_fused<<<BN_TOT, 512, 0, stream>>>(x, masks, pos, Wv, bv,
                                        Vw1, Vb1, Vw2t, Vb2, out);
}